// Round 2
// baseline (342.838 us; speedup 1.0000x reference)
//
#include <hip/hip_runtime.h>
#include <math.h>

// Problem constants: B=256, H=W=64, P=16, PH=PW=16, ZD=32, HD=1024, UD=3, IN=4096
// Mega-kernel: whole pipeline in ONE launch, 256 blocks x 1024 threads
// (1 block/CU, co-resident), manual device-scope grid barriers between phases.
// Numerics are bit-identical to the previous 6-kernel version (same SPLITK=8,
// same k-step order, same 3-chain bf16x3 accumulation, same reduce order).
#define NBLK 256
#define SPLITK 8
#define PSUM_STRIDE 262144   // 256*1024

typedef __bf16 bf16x8 __attribute__((ext_vector_type(8)));
typedef float  f32x16 __attribute__((ext_vector_type(16)));

__device__ __forceinline__ unsigned short bf16rne(float x) {
    unsigned int u = __float_as_uint(x);
    unsigned int r = u + 0x7FFFu + ((u >> 16) & 1u);
    return (unsigned short)(r >> 16);
}
__device__ __forceinline__ float bf16tof(unsigned short h) {
    return __uint_as_float(((unsigned int)h) << 16);
}

// ---------------------------------------------------------------------------
// Device-scope grid barrier (sense-reversing via generation counter).
// bar[0] = arrival counter, bar[32] = generation (128 B apart, separate lines).
// Requires all NBLK blocks co-resident: grid = 256 = #CUs, 1 block/CU.
// Spin has a cap so a logic bug degrades to wrong-answer, not a hang.
// ---------------------------------------------------------------------------
__device__ __forceinline__ void grid_barrier(unsigned int* bar) {
    __syncthreads();
    if (threadIdx.x == 0) {
        __threadfence();   // release all prior global writes (device scope)
        unsigned int gen = __hip_atomic_load(bar + 32, __ATOMIC_RELAXED, __HIP_MEMORY_SCOPE_AGENT);
        unsigned int arrived = __hip_atomic_fetch_add(bar, 1u, __ATOMIC_ACQ_REL, __HIP_MEMORY_SCOPE_AGENT);
        if (arrived == (unsigned int)(NBLK - 1)) {
            __hip_atomic_store(bar, 0u, __ATOMIC_RELAXED, __HIP_MEMORY_SCOPE_AGENT);
            __hip_atomic_store(bar + 32, gen + 1u, __ATOMIC_RELEASE, __HIP_MEMORY_SCOPE_AGENT);
        } else {
            long cap = 0;
            while (__hip_atomic_load(bar + 32, __ATOMIC_ACQUIRE, __HIP_MEMORY_SCOPE_AGENT) == gen) {
                __builtin_amdgcn_s_sleep(2);
                if (++cap > 200000000L) break;
            }
        }
        __threadfence();   // acquire side: invalidate stale cached lines
    }
    __syncthreads();
}

// ---------------------------------------------------------------------------
// GEMM job: 64x64 output tile, 4 waves (2x2), 32x32x16 MFMA, bf16x3 chains,
// BK=32 LDS tiles (16 KB/job), XOR swizzle ch ^ ((row>>1)&3) -- same
// conflict-free bank pattern as the proven BK=64 layout.
// K-step order and chain structure bit-identical to the 6-kernel version.
// "active=false" groups participate only in the barriers (uniform counts).
// ---------------------------------------------------------------------------
__device__ __forceinline__ void gemm_job(
    const unsigned short* __restrict__ Ahi, const unsigned short* __restrict__ Alo,
    const unsigned short* __restrict__ Bhi, const unsigned short* __restrict__ Blo,
    float* __restrict__ psum, int K, int kchunk, int job, int t,
    unsigned short* lds, bool active)
{
    unsigned short* Ah = lds;
    unsigned short* Al = lds + 2048;
    unsigned short* Bh = lds + 4096;
    unsigned short* Bl = lds + 6144;
    int z = job & 7, xy = job >> 3;
    int n0 = (xy & 15) * 64, m0 = (xy >> 4) * 64;
    int kb = z * kchunk;
    int wid = t >> 6, lane = t & 63;
    int wm = wid & 1, wn = wid >> 1;
    int lr = lane & 31, hi = lane >> 5;

    int r0 = t >> 2, ch0 = t & 3;                       // 64 rows x 4 chunks of 16B
    int l0 = r0 * 32 + 8 * (ch0 ^ ((r0 >> 1) & 3));     // ushort index, row stride 64B
    size_t ga = (size_t)(m0 + r0) * K + kb + ch0 * 8;
    size_t gb = (size_t)(n0 + r0) * K + kb + ch0 * 8;

    f32x16 acc_hh = {}, acc_hl = {}, acc_lh = {};
    int nkt = kchunk >> 5;

    uint4 vah, val, vbh, vbl;
    if (active) {
        vah = *(const uint4*)(Ahi + ga);
        val = *(const uint4*)(Alo + ga);
        vbh = *(const uint4*)(Bhi + gb);
        vbl = *(const uint4*)(Blo + gb);
    }

    int basea = (wm * 32 + lr) * 32;
    int baseb = (wn * 32 + lr) * 32;
    int sw = (lr >> 1) & 3;

    for (int kt = 0; kt < nkt; kt++) {
        __syncthreads();
        if (active) {
            *(uint4*)(Ah + l0) = vah;
            *(uint4*)(Al + l0) = val;
            *(uint4*)(Bh + l0) = vbh;
            *(uint4*)(Bl + l0) = vbl;
        }
        __syncthreads();
        if (active) {
            if (kt + 1 < nkt) {
                size_t o = (size_t)(kt + 1) * 32;
                vah = *(const uint4*)(Ahi + ga + o);
                val = *(const uint4*)(Alo + ga + o);
                vbh = *(const uint4*)(Bhi + gb + o);
                vbl = *(const uint4*)(Blo + gb + o);
            }
#pragma unroll
            for (int s = 0; s < 2; s++) {
                int ca = 8 * (((s << 1) + hi) ^ sw);
                bf16x8 afh = *(const bf16x8*)(Ah + basea + ca);
                bf16x8 afl = *(const bf16x8*)(Al + basea + ca);
                bf16x8 bfh = *(const bf16x8*)(Bh + baseb + ca);
                bf16x8 bfl = *(const bf16x8*)(Bl + baseb + ca);
                acc_hh = __builtin_amdgcn_mfma_f32_32x32x16_bf16(afh, bfh, acc_hh, 0, 0, 0);
                acc_hl = __builtin_amdgcn_mfma_f32_32x32x16_bf16(afh, bfl, acc_hl, 0, 0, 0);
                acc_lh = __builtin_amdgcn_mfma_f32_32x32x16_bf16(afl, bfh, acc_lh, 0, 0, 0);
            }
        }
    }
    if (active) {
        // C layout (measured): col = lane&31, row = (r&3) + 8*(r>>2) + 4*(lane>>5)
        float* op = psum + (size_t)z * PSUM_STRIDE;
        int colg = n0 + wn * 32 + lr;
#pragma unroll
        for (int r = 0; r < 16; r++) {
            int rowl = (r & 3) + 8 * (r >> 2) + 4 * hi;
            op[(size_t)(m0 + wm * 32 + rowl) * 1024 + colg] = acc_hh[r] + acc_hl[r] + acc_lh[r];
        }
    }
}

// ---------------------------------------------------------------------------
__global__ __launch_bounds__(1024) void mega(
    const float* __restrict__ inputs, const float* __restrict__ W1,
    const float* __restrict__ b1, const float* __restrict__ W2,
    const float* __restrict__ b2,
    const float* __restrict__ Wum, const float* __restrict__ bum,
    const float* __restrict__ Wuv, const float* __restrict__ buv,
    const float* __restrict__ Wgm, const float* __restrict__ bgm,
    const float* __restrict__ Wgv, const float* __restrict__ bgv,
    const float* __restrict__ Wz, const float* __restrict__ Mm,
    const float* __restrict__ eps_u, const float* __restrict__ eps_g,
    float* __restrict__ out,
    unsigned int* __restrict__ bar,
    float* __restrict__ psum, float* __restrict__ parts_buf, float* __restrict__ WT,
    unsigned short* __restrict__ Ahi, unsigned short* __restrict__ Alo,
    unsigned short* __restrict__ W1Thi, unsigned short* __restrict__ W1Tlo,
    unsigned short* __restrict__ W2Thi, unsigned short* __restrict__ W2Tlo,
    unsigned short* __restrict__ H1hi, unsigned short* __restrict__ H1lo)
{
    __shared__ __align__(16) unsigned char smem[65536];
    int blk = blockIdx.x;
    if (blk >= NBLK) return;
    int tid = threadIdx.x;
    int g = tid >> 8;       // thread-group 0..3 (4 waves each)
    int t = tid & 255;
    int gid = blk * 1024 + tid;

    // ======================= P0: preprocessing =======================
    {
        float (*tile)[33] = (float(*)[33])(smem + g * 4352);
        // W1 [4096,1024] -> transposed bf16 hi/lo split, 32x32 tiles (4096 tiles)
        for (int pass = 0; pass < 4; pass++) {
            int b2t = blk * 16 + pass * 4 + g;
            int n0 = (b2t & 31) * 32, k0 = (b2t >> 5) * 32;
            int c = t & 31, r0 = t >> 5;
#pragma unroll
            for (int i = 0; i < 4; i++)
                tile[r0 + 8 * i][c] = W1[(size_t)(k0 + r0 + 8 * i) * 1024 + n0 + c];
            __syncthreads();
            int kk = t & 31, n1 = t >> 5;
#pragma unroll
            for (int i = 0; i < 4; i++) {
                float x = tile[kk][n1 + 8 * i];
                unsigned short h = bf16rne(x);
                unsigned short l = bf16rne(x - bf16tof(h));
                size_t o = (size_t)(n0 + n1 + 8 * i) * 4096 + k0 + kk;
                W1Thi[o] = h;
                W1Tlo[o] = l;
            }
            __syncthreads();
        }
        // W2 [1024,1024] -> transposed split (1024 tiles)
        {
            int b2t = blk * 4 + g;
            int n0 = (b2t & 31) * 32, k0 = (b2t >> 5) * 32;
            int c = t & 31, r0 = t >> 5;
#pragma unroll
            for (int i = 0; i < 4; i++)
                tile[r0 + 8 * i][c] = W2[(size_t)(k0 + r0 + 8 * i) * 1024 + n0 + c];
            __syncthreads();
            int kk = t & 31, n1 = t >> 5;
#pragma unroll
            for (int i = 0; i < 4; i++) {
                float x = tile[kk][n1 + 8 * i];
                unsigned short h = bf16rne(x);
                unsigned short l = bf16rne(x - bf16tof(h));
                size_t o = (size_t)(n0 + n1 + 8 * i) * 1024 + k0 + kk;
                W2Thi[o] = h;
                W2Tlo[o] = l;
            }
        }
        // inputs fp32 -> bf16 hi/lo, float4-vectorized (exactly 1 float4/thread)
        {
            int id = gid * 4;
            float4 x = *(const float4*)(inputs + id);
            ushort4 h, l;
            h.x = bf16rne(x.x); l.x = bf16rne(x.x - bf16tof(h.x));
            h.y = bf16rne(x.y); l.y = bf16rne(x.y - bf16tof(h.y));
            h.z = bf16rne(x.z); l.z = bf16rne(x.z - bf16tof(h.z));
            h.w = bf16rne(x.w); l.w = bf16rne(x.w - bf16tof(h.w));
            *(ushort4*)(Ahi + id) = h;
            *(ushort4*)(Alo + id) = l;
        }
        // head weights -> k-major WT[102][1024]
        if (gid < 104448) {
            int o = gid >> 10;
            int k = gid & 1023;
            float v;
            if (o < 48)       v = Wum[k * 48 + o];
            else if (o < 96)  v = Wuv[k * 48 + (o - 48)];
            else if (o < 99)  v = Wgm[k * 3 + (o - 96)];
            else              v = Wgv[k * 3 + (o - 99)];
            WT[gid] = v;
        }
        // parts = sigmoid(colsum Wz)
        if (gid < 4096) {
            float s = 0.f;
#pragma unroll
            for (int z = 0; z < 32; z++) s += Wz[z * 4096 + gid];
            parts_buf[gid] = 1.f / (1.f + expf(-s));
        }
    }
    grid_barrier(bar);

    // ======================= P1: MLP layer 1 GEMM =======================
    // jobs = 16(x) x 4(y) x 8(z) = 512 -> groups 0,1 active; 2,3 barrier-only
    gemm_job(Ahi, Alo, W1Thi, W1Tlo, psum, 4096, 4096 / SPLITK,
             blk * 2 + (g & 1), t, (unsigned short*)(smem + g * 16384), g < 2);
    grid_barrier(bar);

    // ======================= P2: reduce + bias + relu + split ============
    {
        float v = psum[gid];
#pragma unroll
        for (int s = 1; s < SPLITK; s++) v += psum[(size_t)s * PSUM_STRIDE + gid];
        v = fmaxf(v + b1[tid], 0.f);
        unsigned short h = bf16rne(v);
        unsigned short l = bf16rne(v - bf16tof(h));
        H1hi[gid] = h;
        H1lo[gid] = l;
    }
    grid_barrier(bar);

    // ======================= P3: MLP layer 2 GEMM =======================
    gemm_job(H1hi, H1lo, W2Thi, W2Tlo, psum, 1024, 1024 / SPLITK,
             blk * 2 + (g & 1), t, (unsigned short*)(smem + g * 16384), g < 2);
    grid_barrier(bar);

    // ======================= P4: heads (per-batch, in-block) =============
    float* patch  = (float*)smem;                    // 4096 f
    float* plane0 = (float*)(smem + 16384);          // 4096 f
    float* plane1 = (float*)(smem + 32768);          // 4096 f
    float* h2     = (float*)(smem + 49152);          // 1024 f
    float* u_raw  = (float*)(smem + 53248);          // 51 f
    float* pc  = (float*)(smem + 53504);
    float* psn = pc + 16;
    float* ptx = pc + 32;
    float* pty = pc + 48;
    float* pwx = pc + 64;
    float* pwy = pc + 80;
    int*   pix = (int*)(pc + 96);
    int*   piy = pix + 16;
    int b = blk;

    {
        float v = psum[(size_t)b * 1024 + tid];
#pragma unroll
        for (int s = 1; s < SPLITK; s++)
            v += psum[(size_t)s * PSUM_STRIDE + (size_t)b * 1024 + tid];
        h2[tid] = fmaxf(v + b2[tid], 0.f);
    }
    for (int i = tid; i < 4096; i += 1024) patch[i] = parts_buf[i];
    __syncthreads();
    {
        int w = tid >> 6, l = tid & 63;
        const float4* h4 = (const float4*)h2;
        float4 hr0 = h4[l], hr1 = h4[64 + l], hr2 = h4[128 + l], hr3 = h4[192 + l];
        for (int o = w; o < 51; o += 16) {
            int rm = (o < 48) ? o : (48 + o);
            int rv = (o < 48) ? (o + 48) : (51 + o);
            const float* wpm = WT + rm * 1024 + l * 4;
            const float* wpv = WT + rv * 1024 + l * 4;
            float4 wm0 = *(const float4*)(wpm);
            float4 wm1 = *(const float4*)(wpm + 256);
            float4 wm2 = *(const float4*)(wpm + 512);
            float4 wm3 = *(const float4*)(wpm + 768);
            float4 wv0 = *(const float4*)(wpv);
            float4 wv1 = *(const float4*)(wpv + 256);
            float4 wv2 = *(const float4*)(wpv + 512);
            float4 wv3 = *(const float4*)(wpv + 768);
            float am = 0.f, av = 0.f;
            am = fmaf(hr0.x, wm0.x, am); am = fmaf(hr0.y, wm0.y, am);
            am = fmaf(hr0.z, wm0.z, am); am = fmaf(hr0.w, wm0.w, am);
            av = fmaf(hr0.x, wv0.x, av); av = fmaf(hr0.y, wv0.y, av);
            av = fmaf(hr0.z, wv0.z, av); av = fmaf(hr0.w, wv0.w, av);
            am = fmaf(hr1.x, wm1.x, am); am = fmaf(hr1.y, wm1.y, am);
            am = fmaf(hr1.z, wm1.z, am); am = fmaf(hr1.w, wm1.w, am);
            av = fmaf(hr1.x, wv1.x, av); av = fmaf(hr1.y, wv1.y, av);
            av = fmaf(hr1.z, wv1.z, av); av = fmaf(hr1.w, wv1.w, av);
            am = fmaf(hr2.x, wm2.x, am); am = fmaf(hr2.y, wm2.y, am);
            am = fmaf(hr2.z, wm2.z, am); am = fmaf(hr2.w, wm2.w, am);
            av = fmaf(hr2.x, wv2.x, av); av = fmaf(hr2.y, wv2.y, av);
            av = fmaf(hr2.z, wv2.z, av); av = fmaf(hr2.w, wv2.w, av);
            am = fmaf(hr3.x, wm3.x, am); am = fmaf(hr3.y, wm3.y, am);
            am = fmaf(hr3.z, wm3.z, am); am = fmaf(hr3.w, wm3.w, am);
            av = fmaf(hr3.x, wv3.x, av); av = fmaf(hr3.y, wv3.y, av);
            av = fmaf(hr3.z, wv3.z, av); av = fmaf(hr3.w, wv3.w, av);
#pragma unroll
            for (int s = 32; s; s >>= 1) {
                am += __shfl_xor(am, s, 64);
                av += __shfl_xor(av, s, 64);
            }
            if (l == 0) {
                if (o < 48) {
                    float umu = tanhf(am + bum[o]);
                    float uvar = expf(fmaxf(av + buv[o], -6.f));   // threshold(-6,-6)
                    u_raw[o] = umu + uvar * eps_u[b * 48 + o];
                } else {
                    int n = o - 48;
                    float gmu = tanhf(am + bgm[n]);
                    float gpre = av + bgv[n];
                    float gvar = expf(gpre > -6.f ? gpre : 6.f);   // threshold(-6,6)
                    u_raw[o] = gmu + gvar * eps_g[b * 3 + n];
                }
            }
        }
    }
    __syncthreads();

    // ======================= P5: compositing + global transform ==========
    if (tid < 16) {
        float ang = u_raw[tid * 3 + 0];
        float tx = u_raw[tid * 3 + 1], ty = u_raw[tid * 3 + 2];
        pc[tid] = cosf(ang);
        psn[tid] = sinf(ang);
        ptx[tid] = tx;
        pty[tid] = ty;
        float ax = fminf(fmaxf(32.f * tx, -16384.f), 16384.f);
        float fax = floorf(ax);
        pwx[tid] = ax - fax;
        pix[tid] = (int)fax;
        float ay = fminf(fmaxf(32.f * ty, -16384.f), 16384.f);
        float fay = floorf(ay);
        pwy[tid] = ay - fay;
        piy[tid] = (int)fay;
    }
    const float* Mb = Mm + ((size_t)(b * 16) << 12);
    ((float4*)plane0)[tid] = ((const float4*)Mb)[tid];
    float4 pfn = ((const float4*)(Mb + 4096))[tid];
    __syncthreads();

    int j = tid & 63;
    int i0 = (tid >> 6) * 4;
    float xnv = (float)(2 * j + 1) * (1.f / 64.f) - 1.f;
    float ynv0 = (float)(2 * i0 + 1) * (1.f / 64.f) - 1.f;

    float num[4] = {}, den[4] = {};
    float* pl_cur = plane0;
    float* pl_nxt = plane1;

    for (int p = 0; p < 16; p++) {
        if (p + 1 < 16) ((float4*)pl_nxt)[tid] = pfn;
        if (p + 2 < 16) pfn = ((const float4*)(Mb + ((size_t)(p + 2) << 12)))[tid];

        int dx = 8 * (p & 3) - 12;
        int dy = 8 * (p >> 2) - 12;
        float c = pc[p], s = psn[p], tx = ptx[p], ty = pty[p];
        float wx = pwx[p], wy = pwy[p];
        int ix = pix[p], iy = piy[p];
        int iY = iy + dy;

        int x0 = j + ix;
        int X = x0 + dx;
        bool vc0 = ((unsigned)x0 < 64u) && ((unsigned)X < 64u);
        bool vc1 = ((unsigned)(x0 + 1) < 64u) && ((unsigned)(X + 1) < 64u);
        float w0 = vc0 ? (1.f - wx) : 0.f;
        float w1 = vc1 ? wx : 0.f;
        int Xc0 = min(max(X, 0), 63);
        int Xc1 = min(max(X + 1, 0), 63);

        const float* pl = pl_cur;
        float R[5];
#pragma unroll
        for (int r = 0; r < 5; r++) {
            int i = i0 + r;
            int ri = i + iY;
            bool vr = ((unsigned)(i + iy) < 64u) && ((unsigned)ri < 64u);
            int ric = min(max(ri, 0), 63);
            const float* row = pl + (ric << 6);
            float val = fmaf(w0, row[Xc0], w1 * row[Xc1]);
            R[r] = vr ? val : 0.f;
        }

        float gx0 = fmaf(-s, ynv0, fmaf(c, xnv, tx));
        float gy0 = fmaf(c, ynv0, fmaf(s, xnv, ty));
        float xs = fmaf(gx0, 32.f, 31.5f);
        float ysv = fmaf(gy0, 32.f, 31.5f);
        int ox = 24 - dx, oy = 24 - dy;
        float oxf = (float)ox, oyf = (float)oy;
        const float* pp = patch + (p << 8);
#pragma unroll
        for (int r = 0; r < 4; r++) {
            float km = fmaf(wy, R[r + 1] - R[r], R[r]);
            den[r] += km;

            if (xs >= oxf - 1.f && xs < oxf + 16.f &&
                ysv >= oyf - 1.f && ysv < oyf + 16.f) {
                float xf = floorf(xs), yf = floorf(ysv);
                float wxx = xs - xf, wyy = ysv - yf;
                int a0 = (int)yf - oy;
                int b0c = (int)xf - ox;
                float v00 = 0.f, v10 = 0.f, v01 = 0.f, v11 = 0.f;
                if ((unsigned)a0 < 16u) {
                    const float* pr = pp + a0 * 16;
                    if ((unsigned)b0c < 16u) v00 = pr[b0c];
                    if ((unsigned)(b0c + 1) < 16u) v10 = pr[b0c + 1];
                }
                if ((unsigned)(a0 + 1) < 16u) {
                    const float* pr = pp + (a0 + 1) * 16;
                    if ((unsigned)b0c < 16u) v01 = pr[b0c];
                    if ((unsigned)(b0c + 1) < 16u) v11 = pr[b0c + 1];
                }
                float top = fmaf(wxx, v10 - v00, v00);
                float bot = fmaf(wxx, v11 - v01, v01);
                float xp = fmaf(wyy, bot - top, top);
                num[r] = fmaf(xp, km, num[r]);
            }
            xs -= s;   // d(xs)/d(row) = -s
            ysv += c;  // d(ys)/d(row) = +c
        }
        __syncthreads();
        float* tmp = pl_cur; pl_cur = pl_nxt; pl_nxt = tmp;
    }

    float* xl = plane0;
#pragma unroll
    for (int r = 0; r < 4; r++) {
        float d = (den[r] == 0.f) ? 1.f : den[r];
        xl[(i0 + r) * 64 + j] = num[r] / d;
    }
    __syncthreads();

    float ang = u_raw[48], gtx = u_raw[49], gty = u_raw[50];
    float cg = cosf(ang), sg = sinf(ang);
    float* ob = out + ((size_t)b << 12);
#pragma unroll
    for (int r = 0; r < 4; r++) {
        int i = i0 + r;
        float ynv = (float)(2 * i + 1) * (1.f / 64.f) - 1.f;
        float gx = cg * xnv - sg * ynv + gtx;
        float gy = sg * xnv + cg * ynv + gty;
        gx = fminf(fmaxf(gx, -8.f), 8.f);
        gy = fminf(fmaxf(gy, -8.f), 8.f);
        float xs = fmaf(gx, 32.f, 31.5f);
        float ysv = fmaf(gy, 32.f, 31.5f);
        float xf = floorf(xs), yf = floorf(ysv);
        float wx = xs - xf, wy = ysv - yf;
        int x0 = (int)xf, y0 = (int)yf;
        float v00 = 0.f, v10 = 0.f, v01 = 0.f, v11 = 0.f;
        bool vx0 = (unsigned)x0 < 64u, vx1 = (unsigned)(x0 + 1) < 64u;
        if ((unsigned)y0 < 64u) {
            const float* row = xl + y0 * 64;
            if (vx0) v00 = row[x0];
            if (vx1) v10 = row[x0 + 1];
        }
        if ((unsigned)(y0 + 1) < 64u) {
            const float* row = xl + (y0 + 1) * 64;
            if (vx0) v01 = row[x0];
            if (vx1) v11 = row[x0 + 1];
        }
        float top = fmaf(wx, v10 - v00, v00);
        float bot = fmaf(wx, v11 - v01, v01);
        ob[i * 64 + j] = fmaf(wy, bot - top, top);
    }
}

// ---------------------------------------------------------------------------
extern "C" void kernel_launch(void* const* d_in, const int* in_sizes, int n_in,
                              void* d_out, int out_size, void* d_ws, size_t ws_size,
                              hipStream_t stream)
{
    (void)in_sizes; (void)n_in; (void)out_size; (void)ws_size;
    const float* inputs = (const float*)d_in[0];
    const float* W1  = (const float*)d_in[1];
    const float* b1  = (const float*)d_in[2];
    const float* W2  = (const float*)d_in[3];
    const float* b2  = (const float*)d_in[4];
    const float* Wum = (const float*)d_in[5];
    const float* bum = (const float*)d_in[6];
    const float* Wuv = (const float*)d_in[7];
    const float* buv = (const float*)d_in[8];
    const float* Wgm = (const float*)d_in[9];
    const float* bgm = (const float*)d_in[10];
    const float* Wgv = (const float*)d_in[11];
    const float* bgv = (const float*)d_in[12];
    const float* Wz  = (const float*)d_in[13];
    const float* Mm  = (const float*)d_in[14];
    const float* eps_u = (const float*)d_in[15];
    const float* eps_g = (const float*)d_in[16];

    unsigned int* bar = (unsigned int*)d_ws;   // 256 B barrier region
    float* ws = (float*)d_ws;
    float* psum      = ws + 64;                 // 8 x 262144 floats
    float* parts_buf = psum + 8 * 262144;       // 4,096
    float* WT_buf    = parts_buf + 4096;        // 104,448
    unsigned short* us = (unsigned short*)(WT_buf + 104448);
    unsigned short* Ahi   = us;                 // 1,048,576
    unsigned short* Alo   = Ahi + 1048576;
    unsigned short* W1Thi = Alo + 1048576;      // 4,194,304
    unsigned short* W1Tlo = W1Thi + 4194304;
    unsigned short* W2Thi = W1Tlo + 4194304;    // 1,048,576
    unsigned short* W2Tlo = W2Thi + 1048576;
    unsigned short* H1hi  = W2Tlo + 1048576;    // 262,144
    unsigned short* H1lo  = H1hi + 262144;

    hipMemsetAsync(d_ws, 0, 256, stream);       // zero barrier counters
    mega<<<dim3(NBLK), dim3(1024), 0, stream>>>(
        inputs, W1, b1, W2, b2, Wum, bum, Wuv, buv, Wgm, bgm, Wgv, bgv,
        Wz, Mm, eps_u, eps_g, (float*)d_out,
        bar, psum, parts_buf, WT_buf,
        Ahi, Alo, W1Thi, W1Tlo, W2Thi, W2Tlo, H1hi, H1lo);
}

// Round 3
// 193.766 us; speedup vs baseline: 1.7693x; 1.7693x over previous
//
#include <hip/hip_runtime.h>
#include <math.h>

// Problem constants: B=256, H=W=64, P=16, PH=PW=16, ZD=32, HD=1024, UD=3, IN=4096
#define SPLITK 8
#define PSUM_STRIDE 262144   // 256*1024

typedef __bf16 bf16x8 __attribute__((ext_vector_type(8)));
typedef float  f32x16 __attribute__((ext_vector_type(16)));

__device__ __forceinline__ unsigned short bf16rne(float x) {
    unsigned int u = __float_as_uint(x);
    unsigned int r = u + 0x7FFFu + ((u >> 16) & 1u);
    return (unsigned short)(r >> 16);
}
__device__ __forceinline__ float bf16tof(unsigned short h) {
    return __uint_as_float(((unsigned int)h) << 16);
}

// ---------------------------------------------------------------------------
// prep_all: fused independent preprocessing.  [r1-proven]
// ---------------------------------------------------------------------------
__global__ __launch_bounds__(256) void prep_all(
    const float* __restrict__ inputs,
    const float* __restrict__ W1, const float* __restrict__ W2,
    const float* __restrict__ Wum, const float* __restrict__ Wuv,
    const float* __restrict__ Wgm, const float* __restrict__ Wgv,
    const float* __restrict__ Wz,
    unsigned short* __restrict__ Ahi, unsigned short* __restrict__ Alo,
    unsigned short* __restrict__ W1Thi, unsigned short* __restrict__ W1Tlo,
    unsigned short* __restrict__ W2Thi, unsigned short* __restrict__ W2Tlo,
    float* __restrict__ WT, float* __restrict__ partsb)
{
    __shared__ float t[32][33];
    int bid = blockIdx.x;
    int tid = threadIdx.x;
    if (bid < 4096 || (bid >= 5120 && bid < 6144)) {
        const float* W = (bid < 4096) ? W1 : W2;
        unsigned short* Thi = (bid < 4096) ? W1Thi : W2Thi;
        unsigned short* Tlo = (bid < 4096) ? W1Tlo : W2Tlo;
        int K = (bid < 4096) ? 4096 : 1024;
        int b2 = (bid < 4096) ? bid : (bid - 5120);
        int n0 = (b2 & 31) * 32, k0 = (b2 >> 5) * 32;
        int c = tid & 31, r0 = tid >> 5;
#pragma unroll
        for (int i = 0; i < 4; i++)
            t[r0 + 8 * i][c] = W[(size_t)(k0 + r0 + 8 * i) * 1024 + n0 + c];
        __syncthreads();
        int kk = tid & 31, n1 = tid >> 5;
#pragma unroll
        for (int i = 0; i < 4; i++) {
            float x = t[kk][n1 + 8 * i];
            unsigned short h = bf16rne(x);
            unsigned short l = bf16rne(x - bf16tof(h));
            size_t o = (size_t)(n0 + n1 + 8 * i) * K + k0 + kk;
            Thi[o] = h;
            Tlo[o] = l;
        }
    } else if (bid < 5120) {
        int id = ((bid - 4096) * 256 + tid) * 4;
        float4 x = *(const float4*)(inputs + id);
        ushort4 h, l;
        h.x = bf16rne(x.x); l.x = bf16rne(x.x - bf16tof(h.x));
        h.y = bf16rne(x.y); l.y = bf16rne(x.y - bf16tof(h.y));
        h.z = bf16rne(x.z); l.z = bf16rne(x.z - bf16tof(h.z));
        h.w = bf16rne(x.w); l.w = bf16rne(x.w - bf16tof(h.w));
        *(ushort4*)(Ahi + id) = h;
        *(ushort4*)(Alo + id) = l;
    } else if (bid < 6552) {
        int id = (bid - 6144) * 256 + tid;
        int o = id >> 10;
        int k = id & 1023;
        float v;
        if (o < 48)       v = Wum[k * 48 + o];
        else if (o < 96)  v = Wuv[k * 48 + (o - 48)];
        else if (o < 99)  v = Wgm[k * 3 + (o - 96)];
        else              v = Wgv[k * 3 + (o - 99)];
        WT[id] = v;
    } else {
        int idx = (bid - 6552) * 256 + tid;
        float s = 0.f;
#pragma unroll
        for (int z = 0; z < 32; z++) s += Wz[z * 4096 + idx];
        partsb[idx] = 1.f / (1.f + expf(-s));
    }
}

// ---------------------------------------------------------------------------
// GEMM bf16x3: 64x64 tile, 4 waves, 32x32x16 MFMA, XOR-swizzled LDS. [r1-proven]
// ---------------------------------------------------------------------------
__global__ __launch_bounds__(256) void gemm_bf16x3(
    const unsigned short* __restrict__ Ahi, const unsigned short* __restrict__ Alo,
    const unsigned short* __restrict__ Bhi, const unsigned short* __restrict__ Blo,
    float* __restrict__ psum, int K, int kchunk)
{
    __shared__ unsigned short Ah[4096], Al[4096], Bh[4096], Bl[4096];
    int tid = threadIdx.x;
    int n0 = blockIdx.x * 64, m0 = blockIdx.y * 64;
    int kb = blockIdx.z * kchunk;
    int wid = tid >> 6, lane = tid & 63;
    int wm = wid & 1, wn = wid >> 1;
    int lr = lane & 31, hi = lane >> 5;

    int r0 = tid >> 3, ch0 = tid & 7;
    int r1 = (tid + 256) >> 3, ch1 = (tid + 256) & 7;
    int l0 = r0 * 64 + 8 * (ch0 ^ (r0 & 7));
    int l1 = r1 * 64 + 8 * (ch1 ^ (r1 & 7));
    size_t ga0 = (size_t)(m0 + r0) * K + kb + ch0 * 8;
    size_t ga1 = (size_t)(m0 + r1) * K + kb + ch1 * 8;
    size_t gb0 = (size_t)(n0 + r0) * K + kb + ch0 * 8;
    size_t gb1 = (size_t)(n0 + r1) * K + kb + ch1 * 8;

    f32x16 acc_hh = {}, acc_hl = {}, acc_lh = {};

    int nkt = kchunk >> 6;
    uint4 vah0, vah1, val0, val1, vbh0, vbh1, vbl0, vbl1;
    vah0 = *(const uint4*)(Ahi + ga0);
    vah1 = *(const uint4*)(Ahi + ga1);
    val0 = *(const uint4*)(Alo + ga0);
    val1 = *(const uint4*)(Alo + ga1);
    vbh0 = *(const uint4*)(Bhi + gb0);
    vbh1 = *(const uint4*)(Bhi + gb1);
    vbl0 = *(const uint4*)(Blo + gb0);
    vbl1 = *(const uint4*)(Blo + gb1);

    int basea = (wm * 32 + lr) * 64;
    int baseb = (wn * 32 + lr) * 64;
    int sw = lr & 7;

    for (int kt = 0; kt < nkt; kt++) {
        __syncthreads();
        *(uint4*)(Ah + l0) = vah0;
        *(uint4*)(Ah + l1) = vah1;
        *(uint4*)(Al + l0) = val0;
        *(uint4*)(Al + l1) = val1;
        *(uint4*)(Bh + l0) = vbh0;
        *(uint4*)(Bh + l1) = vbh1;
        *(uint4*)(Bl + l0) = vbl0;
        *(uint4*)(Bl + l1) = vbl1;
        __syncthreads();
        if (kt + 1 < nkt) {
            size_t o = (size_t)(kt + 1) * 64;
            vah0 = *(const uint4*)(Ahi + ga0 + o);
            vah1 = *(const uint4*)(Ahi + ga1 + o);
            val0 = *(const uint4*)(Alo + ga0 + o);
            val1 = *(const uint4*)(Alo + ga1 + o);
            vbh0 = *(const uint4*)(Bhi + gb0 + o);
            vbh1 = *(const uint4*)(Bhi + gb1 + o);
            vbl0 = *(const uint4*)(Blo + gb0 + o);
            vbl1 = *(const uint4*)(Blo + gb1 + o);
        }
#pragma unroll
        for (int s = 0; s < 4; s++) {
            int cidx = 8 * (((s << 1) + hi) ^ sw);
            bf16x8 afh = *(const bf16x8*)(Ah + basea + cidx);
            bf16x8 afl = *(const bf16x8*)(Al + basea + cidx);
            bf16x8 bfh = *(const bf16x8*)(Bh + baseb + cidx);
            bf16x8 bfl = *(const bf16x8*)(Bl + baseb + cidx);
            acc_hh = __builtin_amdgcn_mfma_f32_32x32x16_bf16(afh, bfh, acc_hh, 0, 0, 0);
            acc_hl = __builtin_amdgcn_mfma_f32_32x32x16_bf16(afh, bfl, acc_hl, 0, 0, 0);
            acc_lh = __builtin_amdgcn_mfma_f32_32x32x16_bf16(afl, bfh, acc_lh, 0, 0, 0);
        }
    }

    float* op = psum + (size_t)blockIdx.z * PSUM_STRIDE;
    int colg = n0 + wn * 32 + lr;
#pragma unroll
    for (int r = 0; r < 16; r++) {
        int rowl = (r & 3) + 8 * (r >> 2) + 4 * hi;
        op[(size_t)(m0 + wm * 32 + rowl) * 1024 + colg] = acc_hh[r] + acc_hl[r] + acc_lh[r];
    }
}

// ---------------------------------------------------------------------------
// Reduce layer-1 partials + bias + relu -> bf16 hi/lo split.  [r1-proven]
// ---------------------------------------------------------------------------
__global__ __launch_bounds__(256) void reduce_bias_relu_split(
    const float* __restrict__ psum, const float* __restrict__ bias,
    unsigned short* __restrict__ hi, unsigned short* __restrict__ lo)
{
    int i = (blockIdx.x * 256 + threadIdx.x) * 4;
    float4 v = *(const float4*)(psum + i);
#pragma unroll
    for (int s = 1; s < SPLITK; s++) {
        float4 t = *(const float4*)(psum + (size_t)s * PSUM_STRIDE + i);
        v.x += t.x; v.y += t.y; v.z += t.z; v.w += t.w;
    }
    float4 bb = *(const float4*)(bias + (i & 1023));
    v.x = fmaxf(v.x + bb.x, 0.f);
    v.y = fmaxf(v.y + bb.y, 0.f);
    v.z = fmaxf(v.z + bb.z, 0.f);
    v.w = fmaxf(v.w + bb.w, 0.f);
    ushort4 h, l;
    h.x = bf16rne(v.x); l.x = bf16rne(v.x - bf16tof(h.x));
    h.y = bf16rne(v.y); l.y = bf16rne(v.y - bf16tof(h.y));
    h.z = bf16rne(v.z); l.z = bf16rne(v.z - bf16tof(h.z));
    h.w = bf16rne(v.w); l.w = bf16rne(v.w - bf16tof(h.w));
    *(ushort4*)(hi + i) = h;
    *(ushort4*)(lo + i) = l;
}

// ---------------------------------------------------------------------------
// composite_heads: heads_v3 fused into composite_final's prologue.
// Block b = batch b: (1) reduce psum row b + bias + relu -> h2 (LDS),
// (2) head matvecs -> u_raw[51] (LDS; mega-verified code, identical
// summation order to heads_v3), (3) compositing + global transform.
// 256 blocks x 1024 threads, ~54 KB LDS.
// ---------------------------------------------------------------------------
__global__ __launch_bounds__(1024) void composite_heads(
    const float* __restrict__ psum, const float* __restrict__ b2,
    const float* __restrict__ WT,
    const float* __restrict__ bum, const float* __restrict__ buv,
    const float* __restrict__ bgm, const float* __restrict__ bgv,
    const float* __restrict__ eps_u, const float* __restrict__ eps_g,
    const float* __restrict__ M, const float* __restrict__ parts,
    float* __restrict__ out)
{
    __shared__ float patch[4096];
    __shared__ float plane[2][4096];
    __shared__ float h2[1024];
    __shared__ float u_raw[51];
    __shared__ float pc[16], psn[16], ptx[16], pty[16], pwx[16], pwy[16];
    __shared__ int pix[16], piy[16];
    int b = blockIdx.x;
    int tid = threadIdx.x;

    // ---- heads prologue: layer-2 reduce for row b ----
    {
        float v = psum[(size_t)b * 1024 + tid];
#pragma unroll
        for (int s = 1; s < SPLITK; s++)
            v += psum[(size_t)s * PSUM_STRIDE + (size_t)b * 1024 + tid];
        h2[tid] = fmaxf(v + b2[tid], 0.f);
    }
    for (int i = tid; i < 4096; i += 1024) patch[i] = parts[i];
    __syncthreads();

    // ---- head matvecs (mega-verified; same order as heads_v3) ----
    {
        int w = tid >> 6, l = tid & 63;
        const float4* h4 = (const float4*)h2;
        float4 hr0 = h4[l], hr1 = h4[64 + l], hr2 = h4[128 + l], hr3 = h4[192 + l];
        for (int o = w; o < 51; o += 16) {
            int rm = (o < 48) ? o : (48 + o);
            int rv = (o < 48) ? (o + 48) : (51 + o);
            const float* wpm = WT + rm * 1024 + l * 4;
            const float* wpv = WT + rv * 1024 + l * 4;
            float4 wm0 = *(const float4*)(wpm);
            float4 wm1 = *(const float4*)(wpm + 256);
            float4 wm2 = *(const float4*)(wpm + 512);
            float4 wm3 = *(const float4*)(wpm + 768);
            float4 wv0 = *(const float4*)(wpv);
            float4 wv1 = *(const float4*)(wpv + 256);
            float4 wv2 = *(const float4*)(wpv + 512);
            float4 wv3 = *(const float4*)(wpv + 768);
            float am = 0.f, av = 0.f;
            am = fmaf(hr0.x, wm0.x, am); am = fmaf(hr0.y, wm0.y, am);
            am = fmaf(hr0.z, wm0.z, am); am = fmaf(hr0.w, wm0.w, am);
            av = fmaf(hr0.x, wv0.x, av); av = fmaf(hr0.y, wv0.y, av);
            av = fmaf(hr0.z, wv0.z, av); av = fmaf(hr0.w, wv0.w, av);
            am = fmaf(hr1.x, wm1.x, am); am = fmaf(hr1.y, wm1.y, am);
            am = fmaf(hr1.z, wm1.z, am); am = fmaf(hr1.w, wm1.w, am);
            av = fmaf(hr1.x, wv1.x, av); av = fmaf(hr1.y, wv1.y, av);
            av = fmaf(hr1.z, wv1.z, av); av = fmaf(hr1.w, wv1.w, av);
            am = fmaf(hr2.x, wm2.x, am); am = fmaf(hr2.y, wm2.y, am);
            am = fmaf(hr2.z, wm2.z, am); am = fmaf(hr2.w, wm2.w, am);
            av = fmaf(hr2.x, wv2.x, av); av = fmaf(hr2.y, wv2.y, av);
            av = fmaf(hr2.z, wv2.z, av); av = fmaf(hr2.w, wv2.w, av);
            am = fmaf(hr3.x, wm3.x, am); am = fmaf(hr3.y, wm3.y, am);
            am = fmaf(hr3.z, wm3.z, am); am = fmaf(hr3.w, wm3.w, am);
            av = fmaf(hr3.x, wv3.x, av); av = fmaf(hr3.y, wv3.y, av);
            av = fmaf(hr3.w, wv3.w, av); av = fmaf(hr3.z, wv3.z, av);
#pragma unroll
            for (int s = 32; s; s >>= 1) {
                am += __shfl_xor(am, s, 64);
                av += __shfl_xor(av, s, 64);
            }
            if (l == 0) {
                if (o < 48) {
                    float umu = tanhf(am + bum[o]);
                    float uvar = expf(fmaxf(av + buv[o], -6.f));   // threshold(-6,-6)
                    u_raw[o] = umu + uvar * eps_u[b * 48 + o];
                } else {
                    int n = o - 48;
                    float gmu = tanhf(am + bgm[n]);
                    float gpre = av + bgv[n];
                    float gvar = expf(gpre > -6.f ? gpre : 6.f);   // threshold(-6,6)
                    u_raw[o] = gmu + gvar * eps_g[b * 3 + n];
                }
            }
        }
    }
    __syncthreads();

    // ---- compositing setup ----
    if (tid < 16) {
        float ang = u_raw[tid * 3 + 0];
        float tx = u_raw[tid * 3 + 1], ty = u_raw[tid * 3 + 2];
        pc[tid] = cosf(ang);
        psn[tid] = sinf(ang);
        ptx[tid] = tx;
        pty[tid] = ty;
        float ax = fminf(fmaxf(32.f * tx, -16384.f), 16384.f);
        float fax = floorf(ax);
        pwx[tid] = ax - fax;
        pix[tid] = (int)fax;
        float ay = fminf(fmaxf(32.f * ty, -16384.f), 16384.f);
        float fay = floorf(ay);
        pwy[tid] = ay - fay;
        piy[tid] = (int)fay;
    }
    const float* Mb = M + ((size_t)(b * 16) << 12);
    ((float4*)plane[0])[tid] = ((const float4*)Mb)[tid];
    float4 pfn = ((const float4*)(Mb + 4096))[tid];
    __syncthreads();

    int j = tid & 63;
    int i0 = (tid >> 6) * 4;
    float xnv = (float)(2 * j + 1) * (1.f / 64.f) - 1.f;
    float ynv0 = (float)(2 * i0 + 1) * (1.f / 64.f) - 1.f;

    float num[4] = {}, den[4] = {};
    float* pl_cur = plane[0];
    float* pl_nxt = plane[1];

    for (int p = 0; p < 16; p++) {
        if (p + 1 < 16) ((float4*)pl_nxt)[tid] = pfn;
        if (p + 2 < 16) pfn = ((const float4*)(Mb + ((size_t)(p + 2) << 12)))[tid];

        int dx = 8 * (p & 3) - 12;
        int dy = 8 * (p >> 2) - 12;
        float c = pc[p], s = psn[p], tx = ptx[p], ty = pty[p];
        float wx = pwx[p], wy = pwy[p];
        int ix = pix[p], iy = piy[p];
        int iY = iy + dy;

        int x0 = j + ix;
        int X = x0 + dx;
        bool vc0 = ((unsigned)x0 < 64u) && ((unsigned)X < 64u);
        bool vc1 = ((unsigned)(x0 + 1) < 64u) && ((unsigned)(X + 1) < 64u);
        float w0 = vc0 ? (1.f - wx) : 0.f;
        float w1 = vc1 ? wx : 0.f;
        int Xc0 = min(max(X, 0), 63);
        int Xc1 = min(max(X + 1, 0), 63);

        const float* pl = pl_cur;
        float R[5];
#pragma unroll
        for (int r = 0; r < 5; r++) {
            int i = i0 + r;
            int ri = i + iY;
            bool vr = ((unsigned)(i + iy) < 64u) && ((unsigned)ri < 64u);
            int ric = min(max(ri, 0), 63);
            const float* row = pl + (ric << 6);
            float val = fmaf(w0, row[Xc0], w1 * row[Xc1]);
            R[r] = vr ? val : 0.f;
        }

        float gx0 = fmaf(-s, ynv0, fmaf(c, xnv, tx));
        float gy0 = fmaf(c, ynv0, fmaf(s, xnv, ty));
        float xs = fmaf(gx0, 32.f, 31.5f);
        float ysv = fmaf(gy0, 32.f, 31.5f);
        int ox = 24 - dx, oy = 24 - dy;
        float oxf = (float)ox, oyf = (float)oy;
        const float* pp = patch + (p << 8);
#pragma unroll
        for (int r = 0; r < 4; r++) {
            float km = fmaf(wy, R[r + 1] - R[r], R[r]);
            den[r] += km;

            if (xs >= oxf - 1.f && xs < oxf + 16.f &&
                ysv >= oyf - 1.f && ysv < oyf + 16.f) {
                float xf = floorf(xs), yf = floorf(ysv);
                float wxx = xs - xf, wyy = ysv - yf;
                int a0 = (int)yf - oy;
                int b0c = (int)xf - ox;
                float v00 = 0.f, v10 = 0.f, v01 = 0.f, v11 = 0.f;
                if ((unsigned)a0 < 16u) {
                    const float* pr = pp + a0 * 16;
                    if ((unsigned)b0c < 16u) v00 = pr[b0c];
                    if ((unsigned)(b0c + 1) < 16u) v10 = pr[b0c + 1];
                }
                if ((unsigned)(a0 + 1) < 16u) {
                    const float* pr = pp + (a0 + 1) * 16;
                    if ((unsigned)b0c < 16u) v01 = pr[b0c];
                    if ((unsigned)(b0c + 1) < 16u) v11 = pr[b0c + 1];
                }
                float top = fmaf(wxx, v10 - v00, v00);
                float bot = fmaf(wxx, v11 - v01, v01);
                float xp = fmaf(wyy, bot - top, top);
                num[r] = fmaf(xp, km, num[r]);
            }
            xs -= s;   // d(xs)/d(row) = -s
            ysv += c;  // d(ys)/d(row) = +c
        }
        __syncthreads();
        float* tmp = pl_cur; pl_cur = pl_nxt; pl_nxt = tmp;
    }

    float* xl = plane[0];
#pragma unroll
    for (int r = 0; r < 4; r++) {
        float d = (den[r] == 0.f) ? 1.f : den[r];
        xl[(i0 + r) * 64 + j] = num[r] / d;
    }
    __syncthreads();

    float ang = u_raw[48], gtx = u_raw[49], gty = u_raw[50];
    float cg = cosf(ang), sg = sinf(ang);
    float* ob = out + ((size_t)b << 12);
#pragma unroll
    for (int r = 0; r < 4; r++) {
        int i = i0 + r;
        float ynv = (float)(2 * i + 1) * (1.f / 64.f) - 1.f;
        float gx = cg * xnv - sg * ynv + gtx;
        float gy = sg * xnv + cg * ynv + gty;
        gx = fminf(fmaxf(gx, -8.f), 8.f);
        gy = fminf(fmaxf(gy, -8.f), 8.f);
        float xs = fmaf(gx, 32.f, 31.5f);
        float ysv = fmaf(gy, 32.f, 31.5f);
        float xf = floorf(xs), yf = floorf(ysv);
        float wx = xs - xf, wy = ysv - yf;
        int x0 = (int)xf, y0 = (int)yf;
        float v00 = 0.f, v10 = 0.f, v01 = 0.f, v11 = 0.f;
        bool vx0 = (unsigned)x0 < 64u, vx1 = (unsigned)(x0 + 1) < 64u;
        if ((unsigned)y0 < 64u) {
            const float* row = xl + y0 * 64;
            if (vx0) v00 = row[x0];
            if (vx1) v10 = row[x0 + 1];
        }
        if ((unsigned)(y0 + 1) < 64u) {
            const float* row = xl + (y0 + 1) * 64;
            if (vx0) v01 = row[x0];
            if (vx1) v11 = row[x0 + 1];
        }
        float top = fmaf(wx, v10 - v00, v00);
        float bot = fmaf(wx, v11 - v01, v01);
        ob[i * 64 + j] = fmaf(wy, bot - top, top);
    }
}

// ---------------------------------------------------------------------------
extern "C" void kernel_launch(void* const* d_in, const int* in_sizes, int n_in,
                              void* d_out, int out_size, void* d_ws, size_t ws_size,
                              hipStream_t stream)
{
    (void)in_sizes; (void)n_in; (void)out_size; (void)ws_size;
    const float* inputs = (const float*)d_in[0];
    const float* W1  = (const float*)d_in[1];
    const float* b1  = (const float*)d_in[2];
    const float* W2  = (const float*)d_in[3];
    const float* b2  = (const float*)d_in[4];
    const float* Wum = (const float*)d_in[5];
    const float* bum = (const float*)d_in[6];
    const float* Wuv = (const float*)d_in[7];
    const float* buv = (const float*)d_in[8];
    const float* Wgm = (const float*)d_in[9];
    const float* bgm = (const float*)d_in[10];
    const float* Wgv = (const float*)d_in[11];
    const float* bgv = (const float*)d_in[12];
    const float* Wz  = (const float*)d_in[13];
    const float* Mm  = (const float*)d_in[14];
    const float* eps_u = (const float*)d_in[15];
    const float* eps_g = (const float*)d_in[16];

    float* ws = (float*)d_ws;
    float* psum      = ws;                     // 8 x 262144 = 2,097,152
    float* parts_buf = psum + 8 * PSUM_STRIDE; // 4,096
    float* WTh_buf   = parts_buf + 4096;       // 104,448
    unsigned short* us = (unsigned short*)(WTh_buf + 104448);
    unsigned short* Ahi   = us;                 // 1,048,576
    unsigned short* Alo   = Ahi + 1048576;
    unsigned short* W1Thi = Alo + 1048576;      // 4,194,304
    unsigned short* W1Tlo = W1Thi + 4194304;
    unsigned short* W2Thi = W1Tlo + 4194304;    // 1,048,576
    unsigned short* W2Tlo = W2Thi + 1048576;
    unsigned short* H1hi  = W2Tlo + 1048576;    // 262,144
    unsigned short* H1lo  = H1hi + 262144;

    // Preprocessing
    prep_all<<<6568, 256, 0, stream>>>(inputs, W1, W2, Wum, Wuv, Wgm, Wgv, Wz,
                                       Ahi, Alo, W1Thi, W1Tlo, W2Thi, W2Tlo,
                                       WTh_buf, parts_buf);

    // MLP layer 1: [256,4096] @ [4096,1024], bf16x3 MFMA split-K=8
    gemm_bf16x3<<<dim3(16, 4, SPLITK), 256, 0, stream>>>(Ahi, Alo, W1Thi, W1Tlo,
                                                         psum, 4096, 4096 / SPLITK);
    reduce_bias_relu_split<<<256, 256, 0, stream>>>(psum, b1, H1hi, H1lo);
    // MLP layer 2: [256,1024] @ [1024,1024], split-K=8
    gemm_bf16x3<<<dim3(16, 4, SPLITK), 256, 0, stream>>>(H1hi, H1lo, W2Thi, W2Tlo,
                                                         psum, 1024, 1024 / SPLITK);
    // Heads + compositing + global transform -> out [256,1,64,64]
    composite_heads<<<256, 1024, 0, stream>>>(psum, b2, WTh_buf, bum, buv,
                                              bgm, bgv, eps_u, eps_g,
                                              Mm, parts_buf, (float*)d_out);
}